// Round 3
// baseline (865.243 us; speedup 1.0000x reference)
//
#include <hip/hip_runtime.h>
#include <stdint.h>

// ---------------------------------------------------------------------------
// UpProj block. Inputs fp32 or bf16 (runtime-detected); compute bf16 MFMA,
// fp32 accumulate; output dtype follows input dtype.
//  unpool(4 convs)x2 == GEMM: M=2048 (8 convs x 256 cout, zero-padded taps),
//  K=4608 (9 taps x 512 cin), N=16384 (16 b x 32x32 px).
//  conv9 == GEMM M=256, K=2304, N=65536.
//  This round: conservative staging (uint4 global->reg->LDS), simple scatter
//  transpose kernels. MFMA fragment maps per m89/m120 (verified).
// ---------------------------------------------------------------------------

typedef __bf16 bf16x8 __attribute__((ext_vector_type(8)));
typedef float floatx4 __attribute__((ext_vector_type(4)));

__device__ __forceinline__ float bf2f(uint32_t u) {
  union { uint32_t i; float f; } v;
  v.i = u << 16;
  return v.f;
}
__device__ __forceinline__ uint16_t f2bf(float f) {
  union { float f; uint32_t i; } v;
  v.f = f;
  uint32_t r = v.i + 0x7fff + ((v.i >> 16) & 1);  // RNE
  return (uint16_t)(r >> 16);
}
__device__ __forceinline__ float load_in(const void* p, size_t i, bool isbf) {
  return isbf ? bf2f(((const uint16_t*)p)[i]) : ((const float*)p)[i];
}

// ---------------- dtype detector ----------------
// bf16 inputs: bits 7..14 of each u32 = low-half bf16 exponent, ~always in
// [100,140] for N(0,1). fp32 inputs: those are mantissa bits, ~16% in band.
__global__ void detect_dtype(const uint32_t* __restrict__ xw, uint32_t* __restrict__ flag) {
  int t = threadIdx.x;
  int cnt = 0;
#pragma unroll
  for (int k = 0; k < 16; ++k) {
    uint32_t u = xw[t + k * 256];
    uint32_t e = (u >> 7) & 0xFF;
    cnt += (e >= 100 && e <= 140) ? 1 : 0;
  }
  __shared__ int rs[256];
  rs[t] = cnt;
  __syncthreads();
  for (int o = 128; o > 0; o >>= 1) {
    if (t < o) rs[t] += rs[t + o];
    __syncthreads();
  }
  if (t == 0) flag[0] = (rs[0] > 2048) ? 1u : 0u;  // 1 = bf16 inputs
}

// ---------------- weight packing ----------------
// Wp[m][k]: m = conv*256+cout (conv 0..7 = A1,B1,C1,D1,A2,B2,C2,D2),
// k = (dy*3+dx)*512 + cin; missing taps of small kernels are zero.
__global__ void pack_w_unpool(const void* wa, const void* wb, const void* wc, const void* wd,
                              const void* we, const void* wf, const void* wg, const void* wh,
                              const uint32_t* __restrict__ flag, uint16_t* __restrict__ Wp) {
  const void* ws[8] = {wa, wb, wc, wd, we, wf, wg, wh};
  const bool isbf = flag[0] != 0;
  int m = blockIdx.y;
  int k = blockIdx.x * 256 + threadIdx.x;
  int conv = m >> 8, cout = m & 255;
  int r = k >> 9, cin = k & 511;
  int dy = r / 3, dx = r - dy * 3;
  int sub = conv & 3;
  int kh = 3 - (sub & 1);   // A:(3,3) B:(2,3) C:(3,2) D:(2,2)
  int kw = 3 - (sub >> 1);
  uint16_t v = 0;
  if (dy < kh && dx < kw)
    v = f2bf(load_in(ws[conv], (size_t)((cout * 512 + cin) * kh + dy) * kw + dx, isbf));
  Wp[(size_t)m * 4608 + k] = v;
}

__global__ void pack_w9(const void* __restrict__ w9, const uint32_t* __restrict__ flag,
                        uint16_t* __restrict__ Wp9) {
  const bool isbf = flag[0] != 0;
  int m = blockIdx.y;
  int k = blockIdx.x * 256 + threadIdx.x;
  int r = k >> 8, cin = k & 255;
  int dy = r / 3, dx = r - dy * 3;
  Wp9[(size_t)m * 2304 + k] = f2bf(load_in(w9, (size_t)((m * 256 + cin) * 3 + dy) * 3 + dx, isbf));
}

__global__ void pack_bias(const void* b1, const void* b2, const void* b3, const void* b4,
                          const void* b5, const void* b6, const void* b7, const void* b8,
                          const void* b9, const uint32_t* __restrict__ flag,
                          float* __restrict__ bpk, float* __restrict__ b9pk) {
  const void* bs[8] = {b1, b2, b3, b4, b5, b6, b7, b8};
  const bool isbf = flag[0] != 0;
  int bx = blockIdx.x, t = threadIdx.x;
  if (bx < 8) bpk[bx * 256 + t] = load_in(bs[bx], t, isbf);
  else b9pk[t] = load_in(b9, t, isbf);
}

// ---------------- pad + NCHW->NHWC for x (simple scatter) ----------------
// xp[b][i][j][c] bf16, i,j in [0,34); interior = x[b][c][i-1][j-1]; borders
// pre-zeroed. One thread per (b,i,j,cgroup-of-8); coalesced uint4 writes.
__global__ void pad_x_kernel(const void* __restrict__ x, const uint32_t* __restrict__ flag,
                             uint16_t* __restrict__ xp) {
  const bool isbf = flag[0] != 0;
  int tid = blockIdx.x * 256 + threadIdx.x;  // 16*32*32*64 = 1,048,576
  int cg = tid & 63;
  int rem = tid >> 6;
  int j = rem & 31; rem >>= 5;
  int i = rem & 31;
  int b = rem >> 5;
  uint16_t v[8];
#pragma unroll
  for (int e = 0; e < 8; ++e) {
    int c = cg * 8 + e;
    v[e] = f2bf(load_in(x, ((size_t)(b * 512 + c) * 32 + i) * 32 + j, isbf));
  }
  *(uint4*)&xp[((size_t)(b * 34 + i + 1) * 34 + (j + 1)) * 512 + cg * 8] = *(const uint4*)v;
}

// ---------------- implicit-GEMM conv ----------------
// MODE 0: unpool (writes y1/y2 interleaved NCHW + bias). MODE 1: conv9 -> z.
template <int CIN, int IMGW_SHIFT, int PIXB_SHIFT, int PADW, int MODE>
__global__ __launch_bounds__(256) void gemm_conv(const uint16_t* __restrict__ Wp,
                                                 const uint16_t* __restrict__ xp,
                                                 const float* __restrict__ bias,
                                                 uint16_t* __restrict__ o0,
                                                 uint16_t* __restrict__ o1) {
  constexpr int K = 9 * CIN;
  constexpr int CC = CIN / 32;
  constexpr int MT = (MODE == 0) ? 16 : 2;
  constexpr int IMGW = 1 << IMGW_SHIFT;
  __shared__ uint16_t As[128 * 32];
  __shared__ uint16_t Bs[128 * 32];

  const int t = threadIdx.x;
  const int wave = t >> 6, lane = t & 63;
  const int mt = blockIdx.x % MT;
  const int nt = blockIdx.x / MT;
  const int n0 = nt * 128;

  // staging map: thread t stages row rr = t>>1, 16 elements at koff = (t&1)*16
  const int rr = t >> 1;
  const int koff = (t & 1) * 16;

  const uint16_t* aRow = Wp + (size_t)(mt * 128 + rr) * K;

  auto pixb = [&](int n) -> size_t {
    int bb = n >> PIXB_SHIFT;
    int rem = n & ((1 << PIXB_SHIFT) - 1);
    int hh = rem >> IMGW_SHIFT;
    int ww = rem & (IMGW - 1);
    return ((size_t)(bb * PADW + hh) * PADW + ww) * CIN;
  };
  const uint16_t* bRow = xp + pixb(n0 + rr);

  floatx4 acc[4][4];
#pragma unroll
  for (int i = 0; i < 4; ++i)
#pragma unroll
    for (int j = 0; j < 4; ++j) acc[i][j] = floatx4{0.f, 0.f, 0.f, 0.f};

  const int wm = wave >> 1, wn = wave & 1;
  const int fl = lane & 15, kg = lane >> 4;

  int kidx = 0;
  for (int r = 0; r < 9; ++r) {
    const int toff = ((r / 3) * PADW + (r - (r / 3) * 3)) * CIN;
    for (int cc = 0; cc < CC; ++cc) {
      // stage A and B: two uint4 (16 bf16) per thread per tile
      uint4 av0 = *(const uint4*)(aRow + kidx + koff);
      uint4 av1 = *(const uint4*)(aRow + kidx + koff + 8);
      uint4 bv0 = *(const uint4*)(bRow + toff + cc * 32 + koff);
      uint4 bv1 = *(const uint4*)(bRow + toff + cc * 32 + koff + 8);
      *(uint4*)&As[rr * 32 + koff] = av0;
      *(uint4*)&As[rr * 32 + koff + 8] = av1;
      *(uint4*)&Bs[rr * 32 + koff] = bv0;
      *(uint4*)&Bs[rr * 32 + koff + 8] = bv1;
      __syncthreads();
      bf16x8 af[4], bfr[4];
#pragma unroll
      for (int i = 0; i < 4; ++i)
        af[i] = *(const bf16x8*)&As[(wm * 64 + i * 16 + fl) * 32 + kg * 8];
#pragma unroll
      for (int j = 0; j < 4; ++j)
        bfr[j] = *(const bf16x8*)&Bs[(wn * 64 + j * 16 + fl) * 32 + kg * 8];
#pragma unroll
      for (int i = 0; i < 4; ++i)
#pragma unroll
        for (int j = 0; j < 4; ++j)
          acc[i][j] = __builtin_amdgcn_mfma_f32_16x16x32_bf16(af[i], bfr[j], acc[i][j], 0, 0, 0);
      __syncthreads();
      kidx += 32;
    }
  }

  // epilogue: C/D layout col=lane&15 (n), row=(lane>>4)*4+reg (m)  [m89]
#pragma unroll
  for (int i = 0; i < 4; ++i) {
#pragma unroll
    for (int reg = 0; reg < 4; ++reg) {
      const int mg = mt * 128 + wm * 64 + i * 16 + kg * 4 + reg;
      const float bv = bias[mg];
      if (MODE == 0) {
        const int conv = mg >> 8, cout = mg & 255;
        const int sub = conv & 3;
        const int ey = sub & 1, ex = sub >> 1;  // A(0,0) B(1,0) C(0,1) D(1,1)
        uint16_t* o = (conv & 4) ? o1 : o0;
#pragma unroll
        for (int j = 0; j < 4; ++j) {
          const int n = n0 + wn * 64 + j * 16 + fl;
          const int bb = n >> 10, hh = (n >> 5) & 31, ww = n & 31;
          o[((size_t)((bb * 256 + cout) * 64 + 2 * hh + ey) << 6) + 2 * ww + ex] =
              f2bf(acc[i][j][reg] + bv);
        }
      } else {
#pragma unroll
        for (int j = 0; j < 4; ++j) {
          const int n = n0 + wn * 64 + j * 16 + fl;
          const int bb = n >> 12, hh = (n >> 6) & 63, ww = n & 63;
          o0[((size_t)((bb * 256 + mg) * 64 + hh) << 6) + ww] = f2bf(acc[i][j][reg] + bv);
        }
      }
    }
  }
}

// ---------------- BN stats: one block per channel ----------------
// out[c] = (scale, shift): norm(v) = scale*v + shift (training-mode biased var)
__global__ void bn_stats(const uint16_t* __restrict__ y, const void* __restrict__ gamma,
                         const void* __restrict__ beta, const uint32_t* __restrict__ flag,
                         float2* __restrict__ out) {
  const bool isbf = flag[0] != 0;
  int c = blockIdx.x, t = threadIdx.x;
  const uint32_t* yu = (const uint32_t*)y;
  float s = 0.f, s2 = 0.f;
  for (int b = 0; b < 16; ++b) {
    size_t base = (size_t)(b * 256 + c) * 2048;  // 4096 bf16 = 2048 u32
#pragma unroll
    for (int k = 0; k < 8; ++k) {
      uint32_t v = yu[base + t + k * 256];
      float lo = bf2f(v & 0xffff), hi = bf2f(v >> 16);
      s += lo + hi;
      s2 += lo * lo + hi * hi;
    }
  }
  __shared__ float rs[256], rs2[256];
  rs[t] = s; rs2[t] = s2;
  __syncthreads();
  for (int off = 128; off > 0; off >>= 1) {
    if (t < off) { rs[t] += rs[t + off]; rs2[t] += rs2[t + off]; }
    __syncthreads();
  }
  if (t == 0) {
    float mean = rs[0] * (1.f / 65536.f);
    float var = rs2[0] * (1.f / 65536.f) - mean * mean;
    float scale = load_in(gamma, c, isbf) * rsqrtf(var + 1e-5f);
    float shift = load_in(beta, c, isbf) - mean * scale;
    out[c] = make_float2(scale, shift);
  }
}

// ------- BN1 + ReLU + NCHW->NHWC pad for conv9 input (simple scatter) -------
__global__ void u_fill(const uint16_t* __restrict__ y1, const float2* __restrict__ st,
                       uint16_t* __restrict__ u) {
  int tid = blockIdx.x * 256 + threadIdx.x;  // 16*64*64*32 = 2,097,152
  int cg = tid & 31;
  int rem = tid >> 5;
  int w = rem & 63; rem >>= 6;
  int h = rem & 63;
  int b = rem >> 6;
  uint16_t v[8];
#pragma unroll
  for (int e = 0; e < 8; ++e) {
    int c = cg * 8 + e;
    float2 ab = st[c];
    float val = fmaxf(ab.x * bf2f(y1[((size_t)(b * 256 + c) * 64 + h) * 64 + w]) + ab.y, 0.f);
    v[e] = f2bf(val);
  }
  *(uint4*)&u[((size_t)(b * 66 + h + 1) * 66 + (w + 1)) * 256 + cg * 8] = *(const uint4*)v;
}

// ---------------- final: relu(BN2(z) + BN12(y2)) -> out (dtype per flag) ----
__global__ void final_kernel(const uint16_t* __restrict__ z, const uint16_t* __restrict__ y2,
                             const float2* __restrict__ st2, const float2* __restrict__ st12,
                             const uint32_t* __restrict__ flag, void* __restrict__ out) {
  const bool isbf = flag[0] != 0;
  size_t idx = ((size_t)blockIdx.x * 256 + threadIdx.x) * 8;
  int c = (int)((idx >> 12) & 255);
  float2 a2 = st2[c], a12 = st12[c];
  uint4 vz = *(const uint4*)(z + idx);
  uint4 vy = *(const uint4*)(y2 + idx);
  float r[8];
  auto proc = [&](uint32_t uz, uint32_t uy, int o) {
    r[o] = fmaxf(a2.x * bf2f(uz & 0xffff) + a2.y + a12.x * bf2f(uy & 0xffff) + a12.y, 0.f);
    r[o + 1] = fmaxf(a2.x * bf2f(uz >> 16) + a2.y + a12.x * bf2f(uy >> 16) + a12.y, 0.f);
  };
  proc(vz.x, vy.x, 0);
  proc(vz.y, vy.y, 2);
  proc(vz.z, vy.z, 4);
  proc(vz.w, vy.w, 6);
  if (isbf) {
    uint4 vo;
    vo.x = (uint32_t)f2bf(r[0]) | ((uint32_t)f2bf(r[1]) << 16);
    vo.y = (uint32_t)f2bf(r[2]) | ((uint32_t)f2bf(r[3]) << 16);
    vo.z = (uint32_t)f2bf(r[4]) | ((uint32_t)f2bf(r[5]) << 16);
    vo.w = (uint32_t)f2bf(r[6]) | ((uint32_t)f2bf(r[7]) << 16);
    *(uint4*)((uint16_t*)out + idx) = vo;
  } else {
    float4* of = (float4*)((float*)out + idx);
    of[0] = make_float4(r[0], r[1], r[2], r[3]);
    of[1] = make_float4(r[4], r[5], r[6], r[7]);
  }
}

// ---------------------------------------------------------------------------
extern "C" void kernel_launch(void* const* d_in, const int* in_sizes, int n_in,
                              void* d_out, int out_size, void* d_ws, size_t ws_size,
                              hipStream_t stream) {
  const void* x = d_in[0];
  const void *w1 = d_in[1], *b1 = d_in[2], *w2 = d_in[3], *b2 = d_in[4];
  const void *w3 = d_in[5], *b3 = d_in[6], *w4 = d_in[7], *b4 = d_in[8];
  const void *w5 = d_in[9], *b5 = d_in[10], *w6 = d_in[11], *b6 = d_in[12];
  const void *w7 = d_in[13], *b7 = d_in[14], *w8 = d_in[15], *b8 = d_in[16];
  const void *w9 = d_in[17], *b9 = d_in[18];
  const void *g11 = d_in[19], *be11 = d_in[20], *g12 = d_in[21], *be12 = d_in[22];
  const void *g2 = d_in[23], *be2 = d_in[24];

  char* ws = (char*)d_ws;
  size_t off = 0;
  auto alloc = [&](size_t bytes) -> char* {
    char* p = ws + off;
    off = (off + bytes + 255) & ~(size_t)255;
    return p;
  };
  const size_t xp_bytes = (size_t)16 * 34 * 34 * 512 * 2;   // 18.94 MB
  const size_t y_bytes = (size_t)16 * 256 * 64 * 64 * 2;    // 33.55 MB
  const size_t u_bytes = (size_t)16 * 66 * 66 * 256 * 2;    // 35.68 MB
  const size_t Wp_bytes = (size_t)2048 * 4608 * 2;          // 18.87 MB

  uint32_t* flag = (uint32_t*)alloc(256);
  uint16_t* Wp9 = (uint16_t*)alloc((size_t)256 * 2304 * 2);
  float* bpk = (float*)alloc(2048 * 4);
  float* b9pk = (float*)alloc(256 * 4);
  float2* st1a = (float2*)alloc(256 * 8);
  float2* st1b = (float2*)alloc(256 * 8);
  float2* st2 = (float2*)alloc(256 * 8);
  uint16_t* y1 = (uint16_t*)alloc(y_bytes);
  uint16_t* y2 = (uint16_t*)alloc(y_bytes);
  uint16_t* Wp = (uint16_t*)alloc(Wp_bytes);
  uint16_t* xp = (uint16_t*)alloc(xp_bytes);
  // aliases (lifetimes disjoint, stream-ordered):
  uint16_t* u = Wp;   // u (35.68 MB) overlays Wp+xp (37.81 MB), dead after gemm1
  uint16_t* z = y1;   // z overlays y1, dead after u_fill
  // total footprint ~106 MB

  detect_dtype<<<1, 256, 0, stream>>>((const uint32_t*)x, flag);

  hipMemsetAsync(xp, 0, xp_bytes, stream);  // borders of padded x

  pack_w_unpool<<<dim3(18, 2048), 256, 0, stream>>>(w1, w2, w3, w4, w5, w6, w7, w8, flag, Wp);
  pack_w9<<<dim3(9, 256), 256, 0, stream>>>(w9, flag, Wp9);
  pack_bias<<<9, 256, 0, stream>>>(b1, b2, b3, b4, b5, b6, b7, b8, b9, flag, bpk, b9pk);
  pad_x_kernel<<<4096, 256, 0, stream>>>(x, flag, xp);

  // unpool GEMM: grid = MT(16) * NT(128)
  gemm_conv<512, 5, 10, 34, 0><<<2048, 256, 0, stream>>>(Wp, xp, bpk, y1, y2);

  bn_stats<<<256, 256, 0, stream>>>(y1, g11, be11, flag, st1a);
  bn_stats<<<256, 256, 0, stream>>>(y2, g12, be12, flag, st1b);

  hipMemsetAsync(u, 0, u_bytes, stream);  // borders of padded u (aliases Wp/xp)

  u_fill<<<8192, 256, 0, stream>>>(y1, st1a, u);

  // conv9 GEMM: grid = MT(2) * NT(512); z aliases y1 (dead after u_fill)
  gemm_conv<256, 6, 12, 66, 1><<<1024, 256, 0, stream>>>(Wp9, u, b9pk, z, nullptr);

  bn_stats<<<256, 256, 0, stream>>>(z, g2, be2, flag, st2);

  final_kernel<<<8192, 256, 0, stream>>>(z, y2, st2, st1b, flag, d_out);
}

// Round 4
// 803.907 us; speedup vs baseline: 1.0763x; 1.0763x over previous
//
#include <hip/hip_runtime.h>
#include <stdint.h>

// ---------------------------------------------------------------------------
// UpProj block. Inputs fp32 or bf16 (runtime-detected); compute bf16 MFMA,
// fp32 accumulate; output dtype follows input dtype.
//  unpool(4 convs)x2 == GEMM: M=2048 (8 convs x 256 cout, zero-padded taps),
//  K=4608 (9 taps x 512 cin), N=16384 (16 b x 32x32 px).
//  conv9 == GEMM M=256, K=2304, N=65536.
//  R4 change: gemm staging via global_load_lds width=16 (m97 ladder step).
//  Everything else identical to the verified R3 kernel.
// ---------------------------------------------------------------------------

typedef __bf16 bf16x8 __attribute__((ext_vector_type(8)));
typedef float floatx4 __attribute__((ext_vector_type(4)));

typedef __attribute__((address_space(3))) uint32_t lds32_t;
typedef __attribute__((address_space(1))) const uint32_t glb32_t;

__device__ __forceinline__ void load_lds16(const uint16_t* g, uint16_t* l) {
  // async global->LDS: per-lane global addr, LDS dest = wave-uniform base + lane*16B
  __builtin_amdgcn_global_load_lds((glb32_t*)g, (lds32_t*)l, 16, 0, 0);
}

__device__ __forceinline__ float bf2f(uint32_t u) {
  union { uint32_t i; float f; } v;
  v.i = u << 16;
  return v.f;
}
__device__ __forceinline__ uint16_t f2bf(float f) {
  union { float f; uint32_t i; } v;
  v.f = f;
  uint32_t r = v.i + 0x7fff + ((v.i >> 16) & 1);  // RNE
  return (uint16_t)(r >> 16);
}
__device__ __forceinline__ float load_in(const void* p, size_t i, bool isbf) {
  return isbf ? bf2f(((const uint16_t*)p)[i]) : ((const float*)p)[i];
}

// ---------------- dtype detector ----------------
__global__ void detect_dtype(const uint32_t* __restrict__ xw, uint32_t* __restrict__ flag) {
  int t = threadIdx.x;
  int cnt = 0;
#pragma unroll
  for (int k = 0; k < 16; ++k) {
    uint32_t u = xw[t + k * 256];
    uint32_t e = (u >> 7) & 0xFF;
    cnt += (e >= 100 && e <= 140) ? 1 : 0;
  }
  __shared__ int rs[256];
  rs[t] = cnt;
  __syncthreads();
  for (int o = 128; o > 0; o >>= 1) {
    if (t < o) rs[t] += rs[t + o];
    __syncthreads();
  }
  if (t == 0) flag[0] = (rs[0] > 2048) ? 1u : 0u;  // 1 = bf16 inputs
}

// ---------------- weight packing ----------------
__global__ void pack_w_unpool(const void* wa, const void* wb, const void* wc, const void* wd,
                              const void* we, const void* wf, const void* wg, const void* wh,
                              const uint32_t* __restrict__ flag, uint16_t* __restrict__ Wp) {
  const void* ws[8] = {wa, wb, wc, wd, we, wf, wg, wh};
  const bool isbf = flag[0] != 0;
  int m = blockIdx.y;
  int k = blockIdx.x * 256 + threadIdx.x;
  int conv = m >> 8, cout = m & 255;
  int r = k >> 9, cin = k & 511;
  int dy = r / 3, dx = r - dy * 3;
  int sub = conv & 3;
  int kh = 3 - (sub & 1);   // A:(3,3) B:(2,3) C:(3,2) D:(2,2)
  int kw = 3 - (sub >> 1);
  uint16_t v = 0;
  if (dy < kh && dx < kw)
    v = f2bf(load_in(ws[conv], (size_t)((cout * 512 + cin) * kh + dy) * kw + dx, isbf));
  Wp[(size_t)m * 4608 + k] = v;
}

__global__ void pack_w9(const void* __restrict__ w9, const uint32_t* __restrict__ flag,
                        uint16_t* __restrict__ Wp9) {
  const bool isbf = flag[0] != 0;
  int m = blockIdx.y;
  int k = blockIdx.x * 256 + threadIdx.x;
  int r = k >> 8, cin = k & 255;
  int dy = r / 3, dx = r - dy * 3;
  Wp9[(size_t)m * 2304 + k] = f2bf(load_in(w9, (size_t)((m * 256 + cin) * 3 + dy) * 3 + dx, isbf));
}

__global__ void pack_bias(const void* b1, const void* b2, const void* b3, const void* b4,
                          const void* b5, const void* b6, const void* b7, const void* b8,
                          const void* b9, const uint32_t* __restrict__ flag,
                          float* __restrict__ bpk, float* __restrict__ b9pk) {
  const void* bs[8] = {b1, b2, b3, b4, b5, b6, b7, b8};
  const bool isbf = flag[0] != 0;
  int bx = blockIdx.x, t = threadIdx.x;
  if (bx < 8) bpk[bx * 256 + t] = load_in(bs[bx], t, isbf);
  else b9pk[t] = load_in(b9, t, isbf);
}

// ---------------- pad + NCHW->NHWC for x (simple scatter) ----------------
__global__ void pad_x_kernel(const void* __restrict__ x, const uint32_t* __restrict__ flag,
                             uint16_t* __restrict__ xp) {
  const bool isbf = flag[0] != 0;
  int tid = blockIdx.x * 256 + threadIdx.x;  // 16*32*32*64 = 1,048,576
  int cg = tid & 63;
  int rem = tid >> 6;
  int j = rem & 31; rem >>= 5;
  int i = rem & 31;
  int b = rem >> 5;
  uint16_t v[8];
#pragma unroll
  for (int e = 0; e < 8; ++e) {
    int c = cg * 8 + e;
    v[e] = f2bf(load_in(x, ((size_t)(b * 512 + c) * 32 + i) * 32 + j, isbf));
  }
  *(uint4*)&xp[((size_t)(b * 34 + i + 1) * 34 + (j + 1)) * 512 + cg * 8] = *(const uint4*)v;
}

// ---------------- implicit-GEMM conv ----------------
// MODE 0: unpool (writes y1/y2 interleaved NCHW + bias). MODE 1: conv9 -> z.
template <int CIN, int IMGW_SHIFT, int PIXB_SHIFT, int PADW, int MODE>
__global__ __launch_bounds__(256) void gemm_conv(const uint16_t* __restrict__ Wp,
                                                 const uint16_t* __restrict__ xp,
                                                 const float* __restrict__ bias,
                                                 uint16_t* __restrict__ o0,
                                                 uint16_t* __restrict__ o1) {
  constexpr int K = 9 * CIN;
  constexpr int CC = CIN / 32;
  constexpr int MT = (MODE == 0) ? 16 : 2;
  constexpr int IMGW = 1 << IMGW_SHIFT;
  __shared__ uint16_t As[128 * 32];
  __shared__ uint16_t Bs[128 * 32];

  const int t = threadIdx.x;
  const int wave = t >> 6, lane = t & 63;
  const int mt = blockIdx.x % MT;
  const int nt = blockIdx.x / MT;
  const int n0 = nt * 128;

  // async-staging map: per wave, rows wave*32 .. wave*32+31; per instruction
  // 64 lanes x 16B = 16 rows x 32B: lane -> (row = lane>>2, chunk = lane&3)
  const int chunk = lane & 3;
  const int srow = wave * 32 + (lane >> 2);

  const uint16_t* aSrc0 = Wp + (size_t)(mt * 128 + srow) * K + chunk * 8;
  const uint16_t* aSrc1 = aSrc0 + (size_t)16 * K;

  auto pixb = [&](int n) -> size_t {
    int bb = n >> PIXB_SHIFT;
    int rem = n & ((1 << PIXB_SHIFT) - 1);
    int hh = rem >> IMGW_SHIFT;
    int ww = rem & (IMGW - 1);
    return ((size_t)(bb * PADW + hh) * PADW + ww) * CIN;
  };
  const uint16_t* bSrc0 = xp + pixb(n0 + srow) + chunk * 8;
  const uint16_t* bSrc1 = xp + pixb(n0 + srow + 16) + chunk * 8;

  uint16_t* AsW = &As[(wave * 32) * 32];  // wave-uniform LDS staging base
  uint16_t* BsW = &Bs[(wave * 32) * 32];

  floatx4 acc[4][4];
#pragma unroll
  for (int i = 0; i < 4; ++i)
#pragma unroll
    for (int j = 0; j < 4; ++j) acc[i][j] = floatx4{0.f, 0.f, 0.f, 0.f};

  const int wm = wave >> 1, wn = wave & 1;
  const int fl = lane & 15, kg = lane >> 4;

  int kidx = 0;
  for (int r = 0; r < 9; ++r) {
    const int toff = ((r / 3) * PADW + (r - (r / 3) * 3)) * CIN;
    for (int cc = 0; cc < CC; ++cc) {
      load_lds16(aSrc0 + kidx, AsW);
      load_lds16(aSrc1 + kidx, AsW + 16 * 32);
      load_lds16(bSrc0 + toff + cc * 32, BsW);
      load_lds16(bSrc1 + toff + cc * 32, BsW + 16 * 32);
      __syncthreads();
      bf16x8 af[4], bfr[4];
#pragma unroll
      for (int i = 0; i < 4; ++i)
        af[i] = *(const bf16x8*)&As[(wm * 64 + i * 16 + fl) * 32 + kg * 8];
#pragma unroll
      for (int j = 0; j < 4; ++j)
        bfr[j] = *(const bf16x8*)&Bs[(wn * 64 + j * 16 + fl) * 32 + kg * 8];
#pragma unroll
      for (int i = 0; i < 4; ++i)
#pragma unroll
        for (int j = 0; j < 4; ++j)
          acc[i][j] = __builtin_amdgcn_mfma_f32_16x16x32_bf16(af[i], bfr[j], acc[i][j], 0, 0, 0);
      __syncthreads();
      kidx += 32;
    }
  }

  // epilogue: C/D layout col=lane&15 (n), row=(lane>>4)*4+reg (m)  [m89]
#pragma unroll
  for (int i = 0; i < 4; ++i) {
#pragma unroll
    for (int reg = 0; reg < 4; ++reg) {
      const int mg = mt * 128 + wm * 64 + i * 16 + kg * 4 + reg;
      const float bv = bias[mg];
      if (MODE == 0) {
        const int conv = mg >> 8, cout = mg & 255;
        const int sub = conv & 3;
        const int ey = sub & 1, ex = sub >> 1;  // A(0,0) B(1,0) C(0,1) D(1,1)
        uint16_t* o = (conv & 4) ? o1 : o0;
#pragma unroll
        for (int j = 0; j < 4; ++j) {
          const int n = n0 + wn * 64 + j * 16 + fl;
          const int bb = n >> 10, hh = (n >> 5) & 31, ww = n & 31;
          o[((size_t)((bb * 256 + cout) * 64 + 2 * hh + ey) << 6) + 2 * ww + ex] =
              f2bf(acc[i][j][reg] + bv);
        }
      } else {
#pragma unroll
        for (int j = 0; j < 4; ++j) {
          const int n = n0 + wn * 64 + j * 16 + fl;
          const int bb = n >> 12, hh = (n >> 6) & 63, ww = n & 63;
          o0[((size_t)((bb * 256 + mg) * 64 + hh) << 6) + ww] = f2bf(acc[i][j][reg] + bv);
        }
      }
    }
  }
}

// ---------------- BN stats: one block per channel ----------------
__global__ void bn_stats(const uint16_t* __restrict__ y, const void* __restrict__ gamma,
                         const void* __restrict__ beta, const uint32_t* __restrict__ flag,
                         float2* __restrict__ out) {
  const bool isbf = flag[0] != 0;
  int c = blockIdx.x, t = threadIdx.x;
  const uint32_t* yu = (const uint32_t*)y;
  float s = 0.f, s2 = 0.f;
  for (int b = 0; b < 16; ++b) {
    size_t base = (size_t)(b * 256 + c) * 2048;  // 4096 bf16 = 2048 u32
#pragma unroll
    for (int k = 0; k < 8; ++k) {
      uint32_t v = yu[base + t + k * 256];
      float lo = bf2f(v & 0xffff), hi = bf2f(v >> 16);
      s += lo + hi;
      s2 += lo * lo + hi * hi;
    }
  }
  __shared__ float rs[256], rs2[256];
  rs[t] = s; rs2[t] = s2;
  __syncthreads();
  for (int off = 128; off > 0; off >>= 1) {
    if (t < off) { rs[t] += rs[t + off]; rs2[t] += rs2[t + off]; }
    __syncthreads();
  }
  if (t == 0) {
    float mean = rs[0] * (1.f / 65536.f);
    float var = rs2[0] * (1.f / 65536.f) - mean * mean;
    float scale = load_in(gamma, c, isbf) * rsqrtf(var + 1e-5f);
    float shift = load_in(beta, c, isbf) - mean * scale;
    out[c] = make_float2(scale, shift);
  }
}

// ------- BN1 + ReLU + NCHW->NHWC pad for conv9 input (simple scatter) -------
__global__ void u_fill(const uint16_t* __restrict__ y1, const float2* __restrict__ st,
                       uint16_t* __restrict__ u) {
  int tid = blockIdx.x * 256 + threadIdx.x;  // 16*64*64*32 = 2,097,152
  int cg = tid & 31;
  int rem = tid >> 5;
  int w = rem & 63; rem >>= 6;
  int h = rem & 63;
  int b = rem >> 6;
  uint16_t v[8];
#pragma unroll
  for (int e = 0; e < 8; ++e) {
    int c = cg * 8 + e;
    float2 ab = st[c];
    float val = fmaxf(ab.x * bf2f(y1[((size_t)(b * 256 + c) * 64 + h) * 64 + w]) + ab.y, 0.f);
    v[e] = f2bf(val);
  }
  *(uint4*)&u[((size_t)(b * 66 + h + 1) * 66 + (w + 1)) * 256 + cg * 8] = *(const uint4*)v;
}

// ---------------- final: relu(BN2(z) + BN12(y2)) -> out (dtype per flag) ----
__global__ void final_kernel(const uint16_t* __restrict__ z, const uint16_t* __restrict__ y2,
                             const float2* __restrict__ st2, const float2* __restrict__ st12,
                             const uint32_t* __restrict__ flag, void* __restrict__ out) {
  const bool isbf = flag[0] != 0;
  size_t idx = ((size_t)blockIdx.x * 256 + threadIdx.x) * 8;
  int c = (int)((idx >> 12) & 255);
  float2 a2 = st2[c], a12 = st12[c];
  uint4 vz = *(const uint4*)(z + idx);
  uint4 vy = *(const uint4*)(y2 + idx);
  float r[8];
  auto proc = [&](uint32_t uz, uint32_t uy, int o) {
    r[o] = fmaxf(a2.x * bf2f(uz & 0xffff) + a2.y + a12.x * bf2f(uy & 0xffff) + a12.y, 0.f);
    r[o + 1] = fmaxf(a2.x * bf2f(uz >> 16) + a2.y + a12.x * bf2f(uy >> 16) + a12.y, 0.f);
  };
  proc(vz.x, vy.x, 0);
  proc(vz.y, vy.y, 2);
  proc(vz.z, vy.z, 4);
  proc(vz.w, vy.w, 6);
  if (isbf) {
    uint4 vo;
    vo.x = (uint32_t)f2bf(r[0]) | ((uint32_t)f2bf(r[1]) << 16);
    vo.y = (uint32_t)f2bf(r[2]) | ((uint32_t)f2bf(r[3]) << 16);
    vo.z = (uint32_t)f2bf(r[4]) | ((uint32_t)f2bf(r[5]) << 16);
    vo.w = (uint32_t)f2bf(r[6]) | ((uint32_t)f2bf(r[7]) << 16);
    *(uint4*)((uint16_t*)out + idx) = vo;
  } else {
    float4* of = (float4*)((float*)out + idx);
    of[0] = make_float4(r[0], r[1], r[2], r[3]);
    of[1] = make_float4(r[4], r[5], r[6], r[7]);
  }
}

// ---------------------------------------------------------------------------
extern "C" void kernel_launch(void* const* d_in, const int* in_sizes, int n_in,
                              void* d_out, int out_size, void* d_ws, size_t ws_size,
                              hipStream_t stream) {
  const void* x = d_in[0];
  const void *w1 = d_in[1], *b1 = d_in[2], *w2 = d_in[3], *b2 = d_in[4];
  const void *w3 = d_in[5], *b3 = d_in[6], *w4 = d_in[7], *b4 = d_in[8];
  const void *w5 = d_in[9], *b5 = d_in[10], *w6 = d_in[11], *b6 = d_in[12];
  const void *w7 = d_in[13], *b7 = d_in[14], *w8 = d_in[15], *b8 = d_in[16];
  const void *w9 = d_in[17], *b9 = d_in[18];
  const void *g11 = d_in[19], *be11 = d_in[20], *g12 = d_in[21], *be12 = d_in[22];
  const void *g2 = d_in[23], *be2 = d_in[24];

  char* ws = (char*)d_ws;
  size_t off = 0;
  auto alloc = [&](size_t bytes) -> char* {
    char* p = ws + off;
    off = (off + bytes + 255) & ~(size_t)255;
    return p;
  };
  const size_t xp_bytes = (size_t)16 * 34 * 34 * 512 * 2;   // 18.94 MB
  const size_t y_bytes = (size_t)16 * 256 * 64 * 64 * 2;    // 33.55 MB
  const size_t u_bytes = (size_t)16 * 66 * 66 * 256 * 2;    // 35.68 MB
  const size_t Wp_bytes = (size_t)2048 * 4608 * 2;          // 18.87 MB

  uint32_t* flag = (uint32_t*)alloc(256);
  uint16_t* Wp9 = (uint16_t*)alloc((size_t)256 * 2304 * 2);
  float* bpk = (float*)alloc(2048 * 4);
  float* b9pk = (float*)alloc(256 * 4);
  float2* st1a = (float2*)alloc(256 * 8);
  float2* st1b = (float2*)alloc(256 * 8);
  float2* st2 = (float2*)alloc(256 * 8);
  uint16_t* y1 = (uint16_t*)alloc(y_bytes);
  uint16_t* y2 = (uint16_t*)alloc(y_bytes);
  uint16_t* Wp = (uint16_t*)alloc(Wp_bytes);
  uint16_t* xp = (uint16_t*)alloc(xp_bytes);
  // aliases (lifetimes disjoint, stream-ordered):
  uint16_t* u = Wp;   // u (35.68 MB) overlays Wp+xp (37.81 MB), dead after gemm1
  uint16_t* z = y1;   // z overlays y1, dead after u_fill
  // total footprint ~106 MB

  detect_dtype<<<1, 256, 0, stream>>>((const uint32_t*)x, flag);

  hipMemsetAsync(xp, 0, xp_bytes, stream);  // borders of padded x

  pack_w_unpool<<<dim3(18, 2048), 256, 0, stream>>>(w1, w2, w3, w4, w5, w6, w7, w8, flag, Wp);
  pack_w9<<<dim3(9, 256), 256, 0, stream>>>(w9, flag, Wp9);
  pack_bias<<<9, 256, 0, stream>>>(b1, b2, b3, b4, b5, b6, b7, b8, b9, flag, bpk, b9pk);
  pad_x_kernel<<<4096, 256, 0, stream>>>(x, flag, xp);

  // unpool GEMM: grid = MT(16) * NT(128)
  gemm_conv<512, 5, 10, 34, 0><<<2048, 256, 0, stream>>>(Wp, xp, bpk, y1, y2);

  bn_stats<<<256, 256, 0, stream>>>(y1, g11, be11, flag, st1a);
  bn_stats<<<256, 256, 0, stream>>>(y2, g12, be12, flag, st1b);

  hipMemsetAsync(u, 0, u_bytes, stream);  // borders of padded u (aliases Wp/xp)

  u_fill<<<8192, 256, 0, stream>>>(y1, st1a, u);

  // conv9 GEMM: grid = MT(2) * NT(512); z aliases y1 (dead after u_fill)
  gemm_conv<256, 6, 12, 66, 1><<<1024, 256, 0, stream>>>(Wp9, u, b9pk, z, nullptr);

  bn_stats<<<256, 256, 0, stream>>>(z, g2, be2, flag, st2);

  final_kernel<<<8192, 256, 0, stream>>>(z, y2, st2, st1b, flag, d_out);
}

// Round 5
// 780.054 us; speedup vs baseline: 1.1092x; 1.0306x over previous
//
#include <hip/hip_runtime.h>
#include <stdint.h>

// ---------------------------------------------------------------------------
// UpProj block. Inputs fp32 or bf16 (runtime-detected); compute bf16 MFMA,
// fp32 accumulate; output dtype follows input dtype.
//  unpool(4 convs)x2: per conv-CLASS GEMMs packed into one launch.
//    class A (3,3): M=512 (2 branches x 256), K=4608 (9 taps)
//    class B (2,3): M=512, K=3072 (6 taps, dy<2)
//    class C (3,2): M=512, K=3072 (6 taps, dx<2)
//    class D (2,2): M=512, K=2048 (4 taps)
//  -> 30.6% less MFMA work than the zero-padded M=2048/K=4608 form (R4).
//  conv9 == GEMM M=256, K=2304, N=65536 (unchanged).
//  GEMM block: 128x128 tile, BK=32, global_load_lds width=16,
//  mfma_f32_16x16x32_bf16, 4 waves each 4x4 accumulators.
// ---------------------------------------------------------------------------

typedef __bf16 bf16x8 __attribute__((ext_vector_type(8)));
typedef float floatx4 __attribute__((ext_vector_type(4)));

typedef __attribute__((address_space(3))) uint32_t lds32_t;
typedef __attribute__((address_space(1))) const uint32_t glb32_t;

__device__ __forceinline__ void load_lds16(const uint16_t* g, uint16_t* l) {
  // async global->LDS: per-lane global addr, LDS dest = wave-uniform base + lane*16B
  __builtin_amdgcn_global_load_lds((glb32_t*)g, (lds32_t*)l, 16, 0, 0);
}

__device__ __forceinline__ float bf2f(uint32_t u) {
  union { uint32_t i; float f; } v;
  v.i = u << 16;
  return v.f;
}
__device__ __forceinline__ uint16_t f2bf(float f) {
  union { float f; uint32_t i; } v;
  v.f = f;
  uint32_t r = v.i + 0x7fff + ((v.i >> 16) & 1);  // RNE
  return (uint16_t)(r >> 16);
}
__device__ __forceinline__ float load_in(const void* p, size_t i, bool isbf) {
  return isbf ? bf2f(((const uint16_t*)p)[i]) : ((const float*)p)[i];
}

// class geometry helpers (cls 0=A,1=B,2=C,3=D; ey=cls&1, ex=cls>>1)
__device__ __forceinline__ int cls_ntaps(int cls) { return cls == 0 ? 9 : (cls == 3 ? 4 : 6); }
__device__ __forceinline__ size_t cls_off(int cls) {
  // element offsets of per-class W blocks: 512*{4608,3072,3072,2048} prefix
  return cls == 0 ? 0u : (cls == 1 ? 2359296u : (cls == 2 ? 3932160u : 5505024u));
}
__device__ __forceinline__ void cls_tap(int cls, int r, int& dy, int& dx) {
  if (cls >= 2) { dy = r >> 1; dx = r & 1; }        // kw=2 classes
  else { dy = r / 3; dx = r - 3 * (r / 3); }        // kw=3 classes
}

// ---------------- dtype detector ----------------
__global__ void detect_dtype(const uint32_t* __restrict__ xw, uint32_t* __restrict__ flag) {
  int t = threadIdx.x;
  int cnt = 0;
#pragma unroll
  for (int k = 0; k < 16; ++k) {
    uint32_t u = xw[t + k * 256];
    uint32_t e = (u >> 7) & 0xFF;
    cnt += (e >= 100 && e <= 140) ? 1 : 0;
  }
  __shared__ int rs[256];
  rs[t] = cnt;
  __syncthreads();
  for (int o = 128; o > 0; o >>= 1) {
    if (t < o) rs[t] += rs[t + o];
    __syncthreads();
  }
  if (t == 0) flag[0] = (rs[0] > 2048) ? 1u : 0u;  // 1 = bf16 inputs
}

// ---------------- weight packing (per-class packed K) ----------------
// Wp = concat over cls of [512][Kcls]; row m_local = branch*256 + cout,
// kk = r*512 + cin with r -> (dy,dx) per cls_tap.
__global__ void pack_w_unpool(const void* wa, const void* wb, const void* wc, const void* wd,
                              const void* we, const void* wf, const void* wg, const void* wh,
                              const uint32_t* __restrict__ flag, uint16_t* __restrict__ Wp) {
  const void* ws[8] = {wa, wb, wc, wd, we, wf, wg, wh};  // branch0 A,B,C,D; branch1 A,B,C,D
  const bool isbf = flag[0] != 0;
  int m = blockIdx.y;                       // 0..511
  int kc = blockIdx.x * 256 + threadIdx.x;  // 0..12799 concat K
  int cls, kk;
  if (kc < 4608) { cls = 0; kk = kc; }
  else if (kc < 7680) { cls = 1; kk = kc - 4608; }
  else if (kc < 10752) { cls = 2; kk = kc - 7680; }
  else { cls = 3; kk = kc - 10752; }
  int r = kk >> 9, cin = kk & 511;
  int dy, dx;
  cls_tap(cls, r, dy, dx);
  int branch = m >> 8, cout = m & 255;
  int kh = 3 - (cls & 1), kw = 3 - (cls >> 1);
  int Kcls = cls_ntaps(cls) * 512;
  float v = load_in(ws[branch * 4 + cls], (size_t)((cout * 512 + cin) * kh + dy) * kw + dx, isbf);
  Wp[cls_off(cls) + (size_t)m * Kcls + kk] = f2bf(v);
}

__global__ void pack_w9(const void* __restrict__ w9, const uint32_t* __restrict__ flag,
                        uint16_t* __restrict__ Wp9) {
  const bool isbf = flag[0] != 0;
  int m = blockIdx.y;
  int k = blockIdx.x * 256 + threadIdx.x;
  int r = k >> 8, cin = k & 255;
  int dy = r / 3, dx = r - dy * 3;
  Wp9[(size_t)m * 2304 + k] = f2bf(load_in(w9, (size_t)((m * 256 + cin) * 3 + dy) * 3 + dx, isbf));
}

// bpk layout: [cls][branch][cout] = bpk[cls*512 + branch*256 + cout]
__global__ void pack_bias(const void* b1, const void* b2, const void* b3, const void* b4,
                          const void* b5, const void* b6, const void* b7, const void* b8,
                          const void* b9, const uint32_t* __restrict__ flag,
                          float* __restrict__ bpk, float* __restrict__ b9pk) {
  const void* bs[8] = {b1, b2, b3, b4, b5, b6, b7, b8};
  const bool isbf = flag[0] != 0;
  int bx = blockIdx.x, t = threadIdx.x;
  if (bx < 8) {
    int cls = bx >> 1, branch = bx & 1;
    bpk[bx * 256 + t] = load_in(bs[branch * 4 + cls], t, isbf);
  } else {
    b9pk[t] = load_in(b9, t, isbf);
  }
}

// ---------------- pad + NCHW->NHWC for x (simple scatter) ----------------
__global__ void pad_x_kernel(const void* __restrict__ x, const uint32_t* __restrict__ flag,
                             uint16_t* __restrict__ xp) {
  const bool isbf = flag[0] != 0;
  int tid = blockIdx.x * 256 + threadIdx.x;  // 16*32*32*64 = 1,048,576
  int cg = tid & 63;
  int rem = tid >> 6;
  int j = rem & 31; rem >>= 5;
  int i = rem & 31;
  int b = rem >> 5;
  uint16_t v[8];
#pragma unroll
  for (int e = 0; e < 8; ++e) {
    int c = cg * 8 + e;
    v[e] = f2bf(load_in(x, ((size_t)(b * 512 + c) * 32 + i) * 32 + j, isbf));
  }
  *(uint4*)&xp[((size_t)(b * 34 + i + 1) * 34 + (j + 1)) * 512 + cg * 8] = *(const uint4*)v;
}

// ---------------- implicit-GEMM conv ----------------
// MODE 0: unpool classes (writes y1/y2 interleaved NCHW + bias). MODE 1: conv9.
template <int CIN, int IMGW_SHIFT, int PIXB_SHIFT, int PADW, int MODE>
__global__ __launch_bounds__(256) void gemm_conv(const uint16_t* __restrict__ Wp,
                                                 const uint16_t* __restrict__ xp,
                                                 const float* __restrict__ bias,
                                                 uint16_t* __restrict__ o0,
                                                 uint16_t* __restrict__ o1) {
  constexpr int CC = CIN / 32;  // 32-wide k-chunks per tap
  constexpr int MT = (MODE == 0) ? 16 : 2;
  constexpr int IMGW = 1 << IMGW_SHIFT;
  __shared__ uint16_t As[128 * 32];
  __shared__ uint16_t Bs[128 * 32];

  const int t = threadIdx.x;
  const int wave = t >> 6, lane = t & 63;
  const int mt = blockIdx.x % MT;
  const int nt = blockIdx.x / MT;
  const int n0 = nt * 128;

  // per-class geometry (wave-uniform). MODE 1: single class, 9 taps.
  const int cls = (MODE == 0) ? (mt >> 2) : 0;
  const int ntaps = (MODE == 0) ? cls_ntaps(cls) : 9;
  const int Krow = (MODE == 0) ? ntaps * CIN : 9 * CIN;  // packed row stride
  const int mrow0 = (MODE == 0) ? (mt & 3) * 128 : mt * 128;
  const uint16_t* Wbase = (MODE == 0) ? Wp + cls_off(cls) : Wp;

  // async-staging map: per wave, rows wave*32 .. wave*32+31; per instruction
  // 64 lanes x 16B = 16 rows x 32B: lane -> (row = lane>>2, chunk = lane&3)
  const int chunk = lane & 3;
  const int srow = wave * 32 + (lane >> 2);

  const uint16_t* aSrc0 = Wbase + (size_t)(mrow0 + srow) * Krow + chunk * 8;
  const uint16_t* aSrc1 = aSrc0 + (size_t)16 * Krow;

  auto pixb = [&](int n) -> size_t {
    int bb = n >> PIXB_SHIFT;
    int rem = n & ((1 << PIXB_SHIFT) - 1);
    int hh = rem >> IMGW_SHIFT;
    int ww = rem & (IMGW - 1);
    return ((size_t)(bb * PADW + hh) * PADW + ww) * CIN;
  };
  const uint16_t* bSrc0 = xp + pixb(n0 + srow) + chunk * 8;
  const uint16_t* bSrc1 = xp + pixb(n0 + srow + 16) + chunk * 8;

  uint16_t* AsW = &As[(wave * 32) * 32];  // wave-uniform LDS staging base
  uint16_t* BsW = &Bs[(wave * 32) * 32];

  floatx4 acc[4][4];
#pragma unroll
  for (int i = 0; i < 4; ++i)
#pragma unroll
    for (int j = 0; j < 4; ++j) acc[i][j] = floatx4{0.f, 0.f, 0.f, 0.f};

  const int wm = wave >> 1, wn = wave & 1;
  const int fl = lane & 15, kg = lane >> 4;

  int kidx = 0;
  for (int r = 0; r < ntaps; ++r) {
    int dy, dx;
    if (MODE == 0) cls_tap(cls, r, dy, dx);
    else { dy = r / 3; dx = r - 3 * dy; }
    const int toff = (dy * PADW + dx) * CIN;
    for (int cc = 0; cc < CC; ++cc) {
      load_lds16(aSrc0 + kidx, AsW);
      load_lds16(aSrc1 + kidx, AsW + 16 * 32);
      load_lds16(bSrc0 + toff + cc * 32, BsW);
      load_lds16(bSrc1 + toff + cc * 32, BsW + 16 * 32);
      __syncthreads();
      bf16x8 af[4], bfr[4];
#pragma unroll
      for (int i = 0; i < 4; ++i)
        af[i] = *(const bf16x8*)&As[(wm * 64 + i * 16 + fl) * 32 + kg * 8];
#pragma unroll
      for (int j = 0; j < 4; ++j)
        bfr[j] = *(const bf16x8*)&Bs[(wn * 64 + j * 16 + fl) * 32 + kg * 8];
#pragma unroll
      for (int i = 0; i < 4; ++i)
#pragma unroll
        for (int j = 0; j < 4; ++j)
          acc[i][j] = __builtin_amdgcn_mfma_f32_16x16x32_bf16(af[i], bfr[j], acc[i][j], 0, 0, 0);
      __syncthreads();
      kidx += 32;
    }
  }

  // epilogue: C/D layout col=lane&15 (n), row=(lane>>4)*4+reg (m)  [m89]
#pragma unroll
  for (int i = 0; i < 4; ++i) {
#pragma unroll
    for (int reg = 0; reg < 4; ++reg) {
      const int mloc = mrow0 + wm * 64 + i * 16 + kg * 4 + reg;
      if (MODE == 0) {
        const int branch = mloc >> 8, cout = mloc & 255;
        const int ey = cls & 1, ex = cls >> 1;  // A(0,0) B(1,0) C(0,1) D(1,1)
        const float bv = bias[cls * 512 + mloc];
        uint16_t* o = branch ? o1 : o0;
#pragma unroll
        for (int j = 0; j < 4; ++j) {
          const int n = n0 + wn * 64 + j * 16 + fl;
          const int bb = n >> 10, hh = (n >> 5) & 31, ww = n & 31;
          o[((size_t)((bb * 256 + cout) * 64 + 2 * hh + ey) << 6) + 2 * ww + ex] =
              f2bf(acc[i][j][reg] + bv);
        }
      } else {
        const float bv = bias[mloc];
#pragma unroll
        for (int j = 0; j < 4; ++j) {
          const int n = n0 + wn * 64 + j * 16 + fl;
          const int bb = n >> 12, hh = (n >> 6) & 63, ww = n & 63;
          o0[((size_t)((bb * 256 + mloc) * 64 + hh) << 6) + ww] = f2bf(acc[i][j][reg] + bv);
        }
      }
    }
  }
}

// ---------------- BN stats: one block per channel ----------------
__global__ void bn_stats(const uint16_t* __restrict__ y, const void* __restrict__ gamma,
                         const void* __restrict__ beta, const uint32_t* __restrict__ flag,
                         float2* __restrict__ out) {
  const bool isbf = flag[0] != 0;
  int c = blockIdx.x, t = threadIdx.x;
  const uint32_t* yu = (const uint32_t*)y;
  float s = 0.f, s2 = 0.f;
  for (int b = 0; b < 16; ++b) {
    size_t base = (size_t)(b * 256 + c) * 2048;  // 4096 bf16 = 2048 u32
#pragma unroll
    for (int k = 0; k < 8; ++k) {
      uint32_t v = yu[base + t + k * 256];
      float lo = bf2f(v & 0xffff), hi = bf2f(v >> 16);
      s += lo + hi;
      s2 += lo * lo + hi * hi;
    }
  }
  __shared__ float rs[256], rs2[256];
  rs[t] = s; rs2[t] = s2;
  __syncthreads();
  for (int off = 128; off > 0; off >>= 1) {
    if (t < off) { rs[t] += rs[t + off]; rs2[t] += rs2[t + off]; }
    __syncthreads();
  }
  if (t == 0) {
    float mean = rs[0] * (1.f / 65536.f);
    float var = rs2[0] * (1.f / 65536.f) - mean * mean;
    float scale = load_in(gamma, c, isbf) * rsqrtf(var + 1e-5f);
    float shift = load_in(beta, c, isbf) - mean * scale;
    out[c] = make_float2(scale, shift);
  }
}

// ------- BN1 + ReLU + NCHW->NHWC pad for conv9 input (simple scatter) -------
__global__ void u_fill(const uint16_t* __restrict__ y1, const float2* __restrict__ st,
                       uint16_t* __restrict__ u) {
  int tid = blockIdx.x * 256 + threadIdx.x;  // 16*64*64*32 = 2,097,152
  int cg = tid & 31;
  int rem = tid >> 5;
  int w = rem & 63; rem >>= 6;
  int h = rem & 63;
  int b = rem >> 6;
  uint16_t v[8];
#pragma unroll
  for (int e = 0; e < 8; ++e) {
    int c = cg * 8 + e;
    float2 ab = st[c];
    float val = fmaxf(ab.x * bf2f(y1[((size_t)(b * 256 + c) * 64 + h) * 64 + w]) + ab.y, 0.f);
    v[e] = f2bf(val);
  }
  *(uint4*)&u[((size_t)(b * 66 + h + 1) * 66 + (w + 1)) * 256 + cg * 8] = *(const uint4*)v;
}

// ---------------- final: relu(BN2(z) + BN12(y2)) -> out (dtype per flag) ----
__global__ void final_kernel(const uint16_t* __restrict__ z, const uint16_t* __restrict__ y2,
                             const float2* __restrict__ st2, const float2* __restrict__ st12,
                             const uint32_t* __restrict__ flag, void* __restrict__ out) {
  const bool isbf = flag[0] != 0;
  size_t idx = ((size_t)blockIdx.x * 256 + threadIdx.x) * 8;
  int c = (int)((idx >> 12) & 255);
  float2 a2 = st2[c], a12 = st12[c];
  uint4 vz = *(const uint4*)(z + idx);
  uint4 vy = *(const uint4*)(y2 + idx);
  float r[8];
  auto proc = [&](uint32_t uz, uint32_t uy, int o) {
    r[o] = fmaxf(a2.x * bf2f(uz & 0xffff) + a2.y + a12.x * bf2f(uy & 0xffff) + a12.y, 0.f);
    r[o + 1] = fmaxf(a2.x * bf2f(uz >> 16) + a2.y + a12.x * bf2f(uy >> 16) + a12.y, 0.f);
  };
  proc(vz.x, vy.x, 0);
  proc(vz.y, vy.y, 2);
  proc(vz.z, vy.z, 4);
  proc(vz.w, vy.w, 6);
  if (isbf) {
    uint4 vo;
    vo.x = (uint32_t)f2bf(r[0]) | ((uint32_t)f2bf(r[1]) << 16);
    vo.y = (uint32_t)f2bf(r[2]) | ((uint32_t)f2bf(r[3]) << 16);
    vo.z = (uint32_t)f2bf(r[4]) | ((uint32_t)f2bf(r[5]) << 16);
    vo.w = (uint32_t)f2bf(r[6]) | ((uint32_t)f2bf(r[7]) << 16);
    *(uint4*)((uint16_t*)out + idx) = vo;
  } else {
    float4* of = (float4*)((float*)out + idx);
    of[0] = make_float4(r[0], r[1], r[2], r[3]);
    of[1] = make_float4(r[4], r[5], r[6], r[7]);
  }
}

// ---------------------------------------------------------------------------
extern "C" void kernel_launch(void* const* d_in, const int* in_sizes, int n_in,
                              void* d_out, int out_size, void* d_ws, size_t ws_size,
                              hipStream_t stream) {
  const void* x = d_in[0];
  const void *w1 = d_in[1], *b1 = d_in[2], *w2 = d_in[3], *b2 = d_in[4];
  const void *w3 = d_in[5], *b3 = d_in[6], *w4 = d_in[7], *b4 = d_in[8];
  const void *w5 = d_in[9], *b5 = d_in[10], *w6 = d_in[11], *b6 = d_in[12];
  const void *w7 = d_in[13], *b7 = d_in[14], *w8 = d_in[15], *b8 = d_in[16];
  const void *w9 = d_in[17], *b9 = d_in[18];
  const void *g11 = d_in[19], *be11 = d_in[20], *g12 = d_in[21], *be12 = d_in[22];
  const void *g2 = d_in[23], *be2 = d_in[24];

  char* ws = (char*)d_ws;
  size_t off = 0;
  auto alloc = [&](size_t bytes) -> char* {
    char* p = ws + off;
    off = (off + bytes + 255) & ~(size_t)255;
    return p;
  };
  const size_t xp_bytes = (size_t)16 * 34 * 34 * 512 * 2;   // 18.94 MB
  const size_t y_bytes = (size_t)16 * 256 * 64 * 64 * 2;    // 33.55 MB
  const size_t u_bytes = (size_t)16 * 66 * 66 * 256 * 2;    // 35.68 MB
  const size_t Wp_bytes = (size_t)512 * 12800 * 2;          // 13.11 MB (packed classes)

  uint32_t* flag = (uint32_t*)alloc(256);
  uint16_t* Wp9 = (uint16_t*)alloc((size_t)256 * 2304 * 2);
  float* bpk = (float*)alloc(2048 * 4);
  float* b9pk = (float*)alloc(256 * 4);
  float2* st1a = (float2*)alloc(256 * 8);
  float2* st1b = (float2*)alloc(256 * 8);
  float2* st2 = (float2*)alloc(256 * 8);
  uint16_t* y1 = (uint16_t*)alloc(y_bytes);
  uint16_t* y2 = (uint16_t*)alloc(y_bytes);
  // union region: {Wp + xp} (gemm1 inputs) before gemm1; u (conv9 input) after
  size_t wpal = (Wp_bytes + 255) & ~(size_t)255;
  size_t region_bytes = wpal + xp_bytes;
  if (region_bytes < u_bytes) region_bytes = u_bytes;
  char* region = alloc(region_bytes);
  uint16_t* Wp = (uint16_t*)region;
  uint16_t* xp = (uint16_t*)(region + wpal);
  uint16_t* u = (uint16_t*)region;  // overlays Wp+xp, both dead after gemm1
  uint16_t* z = y1;                 // overlays y1, dead after u_fill
  // total footprint ~103 MB

  detect_dtype<<<1, 256, 0, stream>>>((const uint32_t*)x, flag);

  hipMemsetAsync(xp, 0, xp_bytes, stream);  // borders of padded x

  // packed-class weights: kc in [0,12800) via 50 blocks of 256
  pack_w_unpool<<<dim3(50, 512), 256, 0, stream>>>(w1, w2, w3, w4, w5, w6, w7, w8, flag, Wp);
  pack_w9<<<dim3(9, 256), 256, 0, stream>>>(w9, flag, Wp9);
  pack_bias<<<9, 256, 0, stream>>>(b1, b2, b3, b4, b5, b6, b7, b8, b9, flag, bpk, b9pk);
  pad_x_kernel<<<4096, 256, 0, stream>>>(x, flag, xp);

  // unpool GEMM: grid = MT(16: 4 classes x 4 m-tiles) * NT(128)
  gemm_conv<512, 5, 10, 34, 0><<<2048, 256, 0, stream>>>(Wp, xp, bpk, y1, y2);

  bn_stats<<<256, 256, 0, stream>>>(y1, g11, be11, flag, st1a);
  bn_stats<<<256, 256, 0, stream>>>(y2, g12, be12, flag, st1b);

  hipMemsetAsync(u, 0, u_bytes, stream);  // borders of padded u (aliases Wp/xp)

  u_fill<<<8192, 256, 0, stream>>>(y1, st1a, u);

  // conv9 GEMM: grid = MT(2) * NT(512); z aliases y1 (dead after u_fill)
  gemm_conv<256, 6, 12, 66, 1><<<1024, 256, 0, stream>>>(Wp9, u, b9pk, z, nullptr);

  bn_stats<<<256, 256, 0, stream>>>(z, g2, be2, flag, st2);

  final_kernel<<<8192, 256, 0, stream>>>(z, y2, st2, st1b, flag, d_out);
}

// Round 6
// 663.046 us; speedup vs baseline: 1.3050x; 1.1765x over previous
//
#include <hip/hip_runtime.h>
#include <stdint.h>

// ---------------------------------------------------------------------------
// UpProj block. Inputs fp32 or bf16 (runtime-detected); compute bf16 MFMA,
// fp32 accumulate; output dtype follows input dtype.
//  unpool(4 convs)x2: per conv-CLASS GEMMs packed into one launch.
//    class A (3,3): M=512, K=4608 | B (2,3): K=3072 | C (3,2): K=3072
//    | D (2,2): K=2048   (N=16384)
//  conv9 == GEMM M=256, K=2304, N=65536.
//  R6: BK=64 per barrier-pair (2x 32-K halves staged per __syncthreads) to
//  halve the vmcnt(0)+barrier drain count (latency-bound per R5 counters);
//  class-major block order so short class-D blocks fill the tail.
// ---------------------------------------------------------------------------

typedef __bf16 bf16x8 __attribute__((ext_vector_type(8)));
typedef float floatx4 __attribute__((ext_vector_type(4)));

typedef __attribute__((address_space(3))) uint32_t lds32_t;
typedef __attribute__((address_space(1))) const uint32_t glb32_t;

__device__ __forceinline__ void load_lds16(const uint16_t* g, uint16_t* l) {
  // async global->LDS: per-lane global addr, LDS dest = wave-uniform base + lane*16B
  __builtin_amdgcn_global_load_lds((glb32_t*)g, (lds32_t*)l, 16, 0, 0);
}

__device__ __forceinline__ float bf2f(uint32_t u) {
  union { uint32_t i; float f; } v;
  v.i = u << 16;
  return v.f;
}
__device__ __forceinline__ uint16_t f2bf(float f) {
  union { float f; uint32_t i; } v;
  v.f = f;
  uint32_t r = v.i + 0x7fff + ((v.i >> 16) & 1);  // RNE
  return (uint16_t)(r >> 16);
}
__device__ __forceinline__ float load_in(const void* p, size_t i, bool isbf) {
  return isbf ? bf2f(((const uint16_t*)p)[i]) : ((const float*)p)[i];
}

// class geometry helpers (cls 0=A,1=B,2=C,3=D; ey=cls&1, ex=cls>>1)
__device__ __forceinline__ int cls_ntaps(int cls) { return cls == 0 ? 9 : (cls == 3 ? 4 : 6); }
__device__ __forceinline__ size_t cls_off(int cls) {
  // element offsets of per-class W blocks: 512*{4608,3072,3072,2048} prefix
  return cls == 0 ? 0u : (cls == 1 ? 2359296u : (cls == 2 ? 3932160u : 5505024u));
}
__device__ __forceinline__ void cls_tap(int cls, int r, int& dy, int& dx) {
  if (cls >= 2) { dy = r >> 1; dx = r & 1; }        // kw=2 classes
  else { dy = r / 3; dx = r - 3 * (r / 3); }        // kw=3 classes
}

// ---------------- dtype detector ----------------
__global__ void detect_dtype(const uint32_t* __restrict__ xw, uint32_t* __restrict__ flag) {
  int t = threadIdx.x;
  int cnt = 0;
#pragma unroll
  for (int k = 0; k < 16; ++k) {
    uint32_t u = xw[t + k * 256];
    uint32_t e = (u >> 7) & 0xFF;
    cnt += (e >= 100 && e <= 140) ? 1 : 0;
  }
  __shared__ int rs[256];
  rs[t] = cnt;
  __syncthreads();
  for (int o = 128; o > 0; o >>= 1) {
    if (t < o) rs[t] += rs[t + o];
    __syncthreads();
  }
  if (t == 0) flag[0] = (rs[0] > 2048) ? 1u : 0u;  // 1 = bf16 inputs
}

// ---------------- weight packing (per-class packed K) ----------------
__global__ void pack_w_unpool(const void* wa, const void* wb, const void* wc, const void* wd,
                              const void* we, const void* wf, const void* wg, const void* wh,
                              const uint32_t* __restrict__ flag, uint16_t* __restrict__ Wp) {
  const void* ws[8] = {wa, wb, wc, wd, we, wf, wg, wh};  // branch0 A,B,C,D; branch1 A,B,C,D
  const bool isbf = flag[0] != 0;
  int m = blockIdx.y;                       // 0..511
  int kc = blockIdx.x * 256 + threadIdx.x;  // 0..12799 concat K
  int cls, kk;
  if (kc < 4608) { cls = 0; kk = kc; }
  else if (kc < 7680) { cls = 1; kk = kc - 4608; }
  else if (kc < 10752) { cls = 2; kk = kc - 7680; }
  else { cls = 3; kk = kc - 10752; }
  int r = kk >> 9, cin = kk & 511;
  int dy, dx;
  cls_tap(cls, r, dy, dx);
  int branch = m >> 8, cout = m & 255;
  int kh = 3 - (cls & 1), kw = 3 - (cls >> 1);
  int Kcls = cls_ntaps(cls) * 512;
  float v = load_in(ws[branch * 4 + cls], (size_t)((cout * 512 + cin) * kh + dy) * kw + dx, isbf);
  Wp[cls_off(cls) + (size_t)m * Kcls + kk] = f2bf(v);
}

__global__ void pack_w9(const void* __restrict__ w9, const uint32_t* __restrict__ flag,
                        uint16_t* __restrict__ Wp9) {
  const bool isbf = flag[0] != 0;
  int m = blockIdx.y;
  int k = blockIdx.x * 256 + threadIdx.x;
  int r = k >> 8, cin = k & 255;
  int dy = r / 3, dx = r - dy * 3;
  Wp9[(size_t)m * 2304 + k] = f2bf(load_in(w9, (size_t)((m * 256 + cin) * 3 + dy) * 3 + dx, isbf));
}

// bpk layout: [cls][branch][cout] = bpk[cls*512 + branch*256 + cout]
__global__ void pack_bias(const void* b1, const void* b2, const void* b3, const void* b4,
                          const void* b5, const void* b6, const void* b7, const void* b8,
                          const void* b9, const uint32_t* __restrict__ flag,
                          float* __restrict__ bpk, float* __restrict__ b9pk) {
  const void* bs[8] = {b1, b2, b3, b4, b5, b6, b7, b8};
  const bool isbf = flag[0] != 0;
  int bx = blockIdx.x, t = threadIdx.x;
  if (bx < 8) {
    int cls = bx >> 1, branch = bx & 1;
    bpk[bx * 256 + t] = load_in(bs[branch * 4 + cls], t, isbf);
  } else {
    b9pk[t] = load_in(b9, t, isbf);
  }
}

// ---------------- pad + NCHW->NHWC for x (simple scatter) ----------------
__global__ void pad_x_kernel(const void* __restrict__ x, const uint32_t* __restrict__ flag,
                             uint16_t* __restrict__ xp) {
  const bool isbf = flag[0] != 0;
  int tid = blockIdx.x * 256 + threadIdx.x;  // 16*32*32*64 = 1,048,576
  int cg = tid & 63;
  int rem = tid >> 6;
  int j = rem & 31; rem >>= 5;
  int i = rem & 31;
  int b = rem >> 5;
  uint16_t v[8];
#pragma unroll
  for (int e = 0; e < 8; ++e) {
    int c = cg * 8 + e;
    v[e] = f2bf(load_in(x, ((size_t)(b * 512 + c) * 32 + i) * 32 + j, isbf));
  }
  *(uint4*)&xp[((size_t)(b * 34 + i + 1) * 34 + (j + 1)) * 512 + cg * 8] = *(const uint4*)v;
}

// ---------------- implicit-GEMM conv, BK=64 ----------------
// MODE 0: unpool classes (writes y1/y2 interleaved NCHW + bias). MODE 1: conv9.
template <int CIN, int IMGW_SHIFT, int PIXB_SHIFT, int PADW, int MODE>
__global__ __launch_bounds__(256) void gemm_conv(const uint16_t* __restrict__ Wp,
                                                 const uint16_t* __restrict__ xp,
                                                 const float* __restrict__ bias,
                                                 uint16_t* __restrict__ o0,
                                                 uint16_t* __restrict__ o1) {
  constexpr int CC2 = CIN / 64;  // 64-wide k-chunks per tap
  constexpr int IMGW = 1 << IMGW_SHIFT;
  // [half][row][32] per matrix: two 32-K halves staged per barrier
  __shared__ uint16_t As[2 * 128 * 32];
  __shared__ uint16_t Bs[2 * 128 * 32];

  const int t = threadIdx.x;
  const int wave = t >> 6, lane = t & 63;

  int cls, mtile, nt;
  if (MODE == 0) {
    cls = blockIdx.x >> 9;            // class-major: A first, D last (tail-filler)
    int within = blockIdx.x & 511;
    mtile = within & 3;
    nt = within >> 2;                 // 4 consecutive blocks share B-tile
  } else {
    cls = 0;
    mtile = blockIdx.x & 1;
    nt = blockIdx.x >> 1;
  }
  const int n0 = nt * 128;
  const int ntaps = (MODE == 0) ? cls_ntaps(cls) : 9;
  const int Krow = (MODE == 0) ? ntaps * CIN : 9 * CIN;  // packed row stride
  const int mrow0 = mtile * 128;
  const uint16_t* Wbase = (MODE == 0) ? Wp + cls_off(cls) : Wp;

  // async-staging map per 32-K half: 64 lanes x 16B = 16 rows x 64B;
  // lane -> (row = lane>>2, chunk = lane&3)
  const int chunk = lane & 3;
  const int srow = wave * 32 + (lane >> 2);

  const uint16_t* aSrc0 = Wbase + (size_t)(mrow0 + srow) * Krow + chunk * 8;
  const uint16_t* aSrc1 = aSrc0 + (size_t)16 * Krow;

  auto pixb = [&](int n) -> size_t {
    int bb = n >> PIXB_SHIFT;
    int rem = n & ((1 << PIXB_SHIFT) - 1);
    int hh = rem >> IMGW_SHIFT;
    int ww = rem & (IMGW - 1);
    return ((size_t)(bb * PADW + hh) * PADW + ww) * CIN;
  };
  const uint16_t* bSrc0 = xp + pixb(n0 + srow) + chunk * 8;
  const uint16_t* bSrc1 = xp + pixb(n0 + srow + 16) + chunk * 8;

  // wave-uniform LDS staging bases, per half
  uint16_t* As0W = &As[(wave * 32) * 32];
  uint16_t* As1W = As0W + 128 * 32;
  uint16_t* Bs0W = &Bs[(wave * 32) * 32];
  uint16_t* Bs1W = Bs0W + 128 * 32;

  floatx4 acc[4][4];
#pragma unroll
  for (int i = 0; i < 4; ++i)
#pragma unroll
    for (int j = 0; j < 4; ++j) acc[i][j] = floatx4{0.f, 0.f, 0.f, 0.f};

  const int wm = wave >> 1, wn = wave & 1;
  const int fl = lane & 15, kg = lane >> 4;

  int kidx = 0;
  for (int r = 0; r < ntaps; ++r) {
    int dy, dx;
    if (MODE == 0) cls_tap(cls, r, dy, dx);
    else { dy = r / 3; dx = r - 3 * dy; }
    const int toff = (dy * PADW + dx) * CIN;
    for (int cc = 0; cc < CC2; ++cc) {
      load_lds16(aSrc0 + kidx, As0W);
      load_lds16(aSrc1 + kidx, As0W + 16 * 32);
      load_lds16(aSrc0 + kidx + 32, As1W);
      load_lds16(aSrc1 + kidx + 32, As1W + 16 * 32);
      const int bo = toff + cc * 64;
      load_lds16(bSrc0 + bo, Bs0W);
      load_lds16(bSrc1 + bo, Bs0W + 16 * 32);
      load_lds16(bSrc0 + bo + 32, Bs1W);
      load_lds16(bSrc1 + bo + 32, Bs1W + 16 * 32);
      __syncthreads();
#pragma unroll
      for (int h = 0; h < 2; ++h) {
        bf16x8 af[4], bfr[4];
#pragma unroll
        for (int i = 0; i < 4; ++i)
          af[i] = *(const bf16x8*)&As[h * 4096 + (wm * 64 + i * 16 + fl) * 32 + kg * 8];
#pragma unroll
        for (int j = 0; j < 4; ++j)
          bfr[j] = *(const bf16x8*)&Bs[h * 4096 + (wn * 64 + j * 16 + fl) * 32 + kg * 8];
#pragma unroll
        for (int i = 0; i < 4; ++i)
#pragma unroll
          for (int j = 0; j < 4; ++j)
            acc[i][j] = __builtin_amdgcn_mfma_f32_16x16x32_bf16(af[i], bfr[j], acc[i][j], 0, 0, 0);
      }
      __syncthreads();
      kidx += 64;
    }
  }

  // epilogue: C/D layout col=lane&15 (n), row=(lane>>4)*4+reg (m)  [m89]
#pragma unroll
  for (int i = 0; i < 4; ++i) {
#pragma unroll
    for (int reg = 0; reg < 4; ++reg) {
      const int mloc = mrow0 + wm * 64 + i * 16 + kg * 4 + reg;
      if (MODE == 0) {
        const int branch = mloc >> 8, cout = mloc & 255;
        const int ey = cls & 1, ex = cls >> 1;  // A(0,0) B(1,0) C(0,1) D(1,1)
        const float bv = bias[cls * 512 + mloc];
        uint16_t* o = branch ? o1 : o0;
#pragma unroll
        for (int j = 0; j < 4; ++j) {
          const int n = n0 + wn * 64 + j * 16 + fl;
          const int bb = n >> 10, hh = (n >> 5) & 31, ww = n & 31;
          o[((size_t)((bb * 256 + cout) * 64 + 2 * hh + ey) << 6) + 2 * ww + ex] =
              f2bf(acc[i][j][reg] + bv);
        }
      } else {
        const float bv = bias[mloc];
#pragma unroll
        for (int j = 0; j < 4; ++j) {
          const int n = n0 + wn * 64 + j * 16 + fl;
          const int bb = n >> 12, hh = (n >> 6) & 63, ww = n & 63;
          o0[((size_t)((bb * 256 + mloc) * 64 + hh) << 6) + ww] = f2bf(acc[i][j][reg] + bv);
        }
      }
    }
  }
}

// ---------------- BN stats: one block per channel ----------------
__global__ void bn_stats(const uint16_t* __restrict__ y, const void* __restrict__ gamma,
                         const void* __restrict__ beta, const uint32_t* __restrict__ flag,
                         float2* __restrict__ out) {
  const bool isbf = flag[0] != 0;
  int c = blockIdx.x, t = threadIdx.x;
  const uint32_t* yu = (const uint32_t*)y;
  float s = 0.f, s2 = 0.f;
  for (int b = 0; b < 16; ++b) {
    size_t base = (size_t)(b * 256 + c) * 2048;  // 4096 bf16 = 2048 u32
#pragma unroll
    for (int k = 0; k < 8; ++k) {
      uint32_t v = yu[base + t + k * 256];
      float lo = bf2f(v & 0xffff), hi = bf2f(v >> 16);
      s += lo + hi;
      s2 += lo * lo + hi * hi;
    }
  }
  __shared__ float rs[256], rs2[256];
  rs[t] = s; rs2[t] = s2;
  __syncthreads();
  for (int off = 128; off > 0; off >>= 1) {
    if (t < off) { rs[t] += rs[t + off]; rs2[t] += rs2[t + off]; }
    __syncthreads();
  }
  if (t == 0) {
    float mean = rs[0] * (1.f / 65536.f);
    float var = rs2[0] * (1.f / 65536.f) - mean * mean;
    float scale = load_in(gamma, c, isbf) * rsqrtf(var + 1e-5f);
    float shift = load_in(beta, c, isbf) - mean * scale;
    out[c] = make_float2(scale, shift);
  }
}

// ------- BN1 + ReLU + NCHW->NHWC pad for conv9 input (simple scatter) -------
__global__ void u_fill(const uint16_t* __restrict__ y1, const float2* __restrict__ st,
                       uint16_t* __restrict__ u) {
  int tid = blockIdx.x * 256 + threadIdx.x;  // 16*64*64*32 = 2,097,152
  int cg = tid & 31;
  int rem = tid >> 5;
  int w = rem & 63; rem >>= 6;
  int h = rem & 63;
  int b = rem >> 6;
  uint16_t v[8];
#pragma unroll
  for (int e = 0; e < 8; ++e) {
    int c = cg * 8 + e;
    float2 ab = st[c];
    float val = fmaxf(ab.x * bf2f(y1[((size_t)(b * 256 + c) * 64 + h) * 64 + w]) + ab.y, 0.f);
    v[e] = f2bf(val);
  }
  *(uint4*)&u[((size_t)(b * 66 + h + 1) * 66 + (w + 1)) * 256 + cg * 8] = *(const uint4*)v;
}

// ---------------- final: relu(BN2(z) + BN12(y2)) -> out (dtype per flag) ----
__global__ void final_kernel(const uint16_t* __restrict__ z, const uint16_t* __restrict__ y2,
                             const float2* __restrict__ st2, const float2* __restrict__ st12,
                             const uint32_t* __restrict__ flag, void* __restrict__ out) {
  const bool isbf = flag[0] != 0;
  size_t idx = ((size_t)blockIdx.x * 256 + threadIdx.x) * 8;
  int c = (int)((idx >> 12) & 255);
  float2 a2 = st2[c], a12 = st12[c];
  uint4 vz = *(const uint4*)(z + idx);
  uint4 vy = *(const uint4*)(y2 + idx);
  float r[8];
  auto proc = [&](uint32_t uz, uint32_t uy, int o) {
    r[o] = fmaxf(a2.x * bf2f(uz & 0xffff) + a2.y + a12.x * bf2f(uy & 0xffff) + a12.y, 0.f);
    r[o + 1] = fmaxf(a2.x * bf2f(uz >> 16) + a2.y + a12.x * bf2f(uy >> 16) + a12.y, 0.f);
  };
  proc(vz.x, vy.x, 0);
  proc(vz.y, vy.y, 2);
  proc(vz.z, vy.z, 4);
  proc(vz.w, vy.w, 6);
  if (isbf) {
    uint4 vo;
    vo.x = (uint32_t)f2bf(r[0]) | ((uint32_t)f2bf(r[1]) << 16);
    vo.y = (uint32_t)f2bf(r[2]) | ((uint32_t)f2bf(r[3]) << 16);
    vo.z = (uint32_t)f2bf(r[4]) | ((uint32_t)f2bf(r[5]) << 16);
    vo.w = (uint32_t)f2bf(r[6]) | ((uint32_t)f2bf(r[7]) << 16);
    *(uint4*)((uint16_t*)out + idx) = vo;
  } else {
    float4* of = (float4*)((float*)out + idx);
    of[0] = make_float4(r[0], r[1], r[2], r[3]);
    of[1] = make_float4(r[4], r[5], r[6], r[7]);
  }
}

// ---------------------------------------------------------------------------
extern "C" void kernel_launch(void* const* d_in, const int* in_sizes, int n_in,
                              void* d_out, int out_size, void* d_ws, size_t ws_size,
                              hipStream_t stream) {
  const void* x = d_in[0];
  const void *w1 = d_in[1], *b1 = d_in[2], *w2 = d_in[3], *b2 = d_in[4];
  const void *w3 = d_in[5], *b3 = d_in[6], *w4 = d_in[7], *b4 = d_in[8];
  const void *w5 = d_in[9], *b5 = d_in[10], *w6 = d_in[11], *b6 = d_in[12];
  const void *w7 = d_in[13], *b7 = d_in[14], *w8 = d_in[15], *b8 = d_in[16];
  const void *w9 = d_in[17], *b9 = d_in[18];
  const void *g11 = d_in[19], *be11 = d_in[20], *g12 = d_in[21], *be12 = d_in[22];
  const void *g2 = d_in[23], *be2 = d_in[24];

  char* ws = (char*)d_ws;
  size_t off = 0;
  auto alloc = [&](size_t bytes) -> char* {
    char* p = ws + off;
    off = (off + bytes + 255) & ~(size_t)255;
    return p;
  };
  const size_t xp_bytes = (size_t)16 * 34 * 34 * 512 * 2;   // 18.94 MB
  const size_t y_bytes = (size_t)16 * 256 * 64 * 64 * 2;    // 33.55 MB
  const size_t u_bytes = (size_t)16 * 66 * 66 * 256 * 2;    // 35.68 MB
  const size_t Wp_bytes = (size_t)512 * 12800 * 2;          // 13.11 MB (packed classes)

  uint32_t* flag = (uint32_t*)alloc(256);
  uint16_t* Wp9 = (uint16_t*)alloc((size_t)256 * 2304 * 2);
  float* bpk = (float*)alloc(2048 * 4);
  float* b9pk = (float*)alloc(256 * 4);
  float2* st1a = (float2*)alloc(256 * 8);
  float2* st1b = (float2*)alloc(256 * 8);
  float2* st2 = (float2*)alloc(256 * 8);
  uint16_t* y1 = (uint16_t*)alloc(y_bytes);
  uint16_t* y2 = (uint16_t*)alloc(y_bytes);
  // union region: {Wp + xp} (gemm1 inputs) before gemm1; u (conv9 input) after
  size_t wpal = (Wp_bytes + 255) & ~(size_t)255;
  size_t region_bytes = wpal + xp_bytes;
  if (region_bytes < u_bytes) region_bytes = u_bytes;
  char* region = alloc(region_bytes);
  uint16_t* Wp = (uint16_t*)region;
  uint16_t* xp = (uint16_t*)(region + wpal);
  uint16_t* u = (uint16_t*)region;  // overlays Wp+xp, both dead after gemm1
  uint16_t* z = y1;                 // overlays y1, dead after u_fill
  // total footprint ~103 MB

  detect_dtype<<<1, 256, 0, stream>>>((const uint32_t*)x, flag);

  hipMemsetAsync(xp, 0, xp_bytes, stream);  // borders of padded x

  // packed-class weights: kc in [0,12800) via 50 blocks of 256
  pack_w_unpool<<<dim3(50, 512), 256, 0, stream>>>(w1, w2, w3, w4, w5, w6, w7, w8, flag, Wp);
  pack_w9<<<dim3(9, 256), 256, 0, stream>>>(w9, flag, Wp9);
  pack_bias<<<9, 256, 0, stream>>>(b1, b2, b3, b4, b5, b6, b7, b8, b9, flag, bpk, b9pk);
  pad_x_kernel<<<4096, 256, 0, stream>>>(x, flag, xp);

  // unpool GEMM: grid = 4 classes x 4 m-tiles x 128 n-tiles (class-major)
  gemm_conv<512, 5, 10, 34, 0><<<2048, 256, 0, stream>>>(Wp, xp, bpk, y1, y2);

  bn_stats<<<256, 256, 0, stream>>>(y1, g11, be11, flag, st1a);
  bn_stats<<<256, 256, 0, stream>>>(y2, g12, be12, flag, st1b);

  hipMemsetAsync(u, 0, u_bytes, stream);  // borders of padded u (aliases Wp/xp)

  u_fill<<<8192, 256, 0, stream>>>(y1, st1a, u);

  // conv9 GEMM: grid = MT(2) * NT(512); z aliases y1 (dead after u_fill)
  gemm_conv<256, 6, 12, 66, 1><<<1024, 256, 0, stream>>>(Wp9, u, b9pk, z, nullptr);

  bn_stats<<<256, 256, 0, stream>>>(z, g2, be2, flag, st2);

  final_kernel<<<8192, 256, 0, stream>>>(z, y2, st2, st1b, flag, d_out);
}